// Round 5
// baseline (589.966 us; speedup 1.0000x reference)
//
#include <hip/hip_runtime.h>
#include <hip/hip_bf16.h>

typedef __bf16 bf16;
typedef __bf16 bf16x4 __attribute__((ext_vector_type(4)));
typedef __bf16 bf16x8 __attribute__((ext_vector_type(8)));
typedef float  floatx4 __attribute__((ext_vector_type(4)));

#define NUM_NODES 2000000
#define NUM_DAGS  20000
#define NE 32

#define MFMA(a, b, c) __builtin_amdgcn_mfma_f32_16x16x32_bf16((a), (b), (c), 0, 0, 0)

#define ROW_BYTES  144                 // 16 nodes/tile, 144 B per node-row
#define TILE_BYTES (16 * ROW_BYTES)    // 2304 B
#define WAVE_LDS   (4 * TILE_BYTES)    // 9216 B: one 64-node group per wave
#define WCHUNK     512                 // nodes per wave (contiguous)
#define NGROUPS    (WCHUNK / 64)       // 8 groups of 64 nodes
#define CHUNK      (4 * WCHUNK)        // 2048 nodes per block

// Find largest s in [0, NUM_DAGS-1] with ptr[s*st] <= n.
// st = 1 for int32 ptr, 2 for int64 (little-endian low words).
__device__ __forceinline__ int seg_of(const int* __restrict__ ptr, int n, int st) {
    int lo = 0, hi = NUM_DAGS;
    while (hi - lo > 1) {
        int mid = (lo + hi) >> 1;
        if (ptr[mid * st] <= n) lo = mid; else hi = mid;
    }
    return lo;
}

// Load activation B-fragments for one 64-node group starting at gBase.
// A0: h_node k=0..31 frag; A1: x/bias k=32..63 frag (only q==0 lanes non-zero).
#define LOADG(gBase, A0, A1)                                                      \
    do {                                                                          \
        _Pragma("unroll")                                                         \
        for (int j_ = 0; j_ < 4; ++j_) {                                          \
            const int node_ = (gBase) + j_ * 16 + mr;                             \
            bf16x8 f_ = {};                                                       \
            bf16x8 g_ = {};                                                       \
            if (node_ < NUM_NODES) {                                              \
                const floatx4* hp_ =                                              \
                    (const floatx4*)(h_node + (size_t)node_ * 32 + q * 8);        \
                floatx4 v0_ = hp_[0], v1_ = hp_[1];                               \
                f_[0] = (bf16)v0_[0]; f_[1] = (bf16)v0_[1];                       \
                f_[2] = (bf16)v0_[2]; f_[3] = (bf16)v0_[3];                       \
                f_[4] = (bf16)v1_[0]; f_[5] = (bf16)v1_[1];                       \
                f_[6] = (bf16)v1_[2]; f_[7] = (bf16)v1_[3];                       \
                if (q == 0) {                                                     \
                    const float* xp_ = x + (size_t)node_ * 5;                     \
                    g_[0] = (bf16)xp_[0]; g_[1] = (bf16)xp_[1];                   \
                    g_[2] = (bf16)xp_[2]; g_[3] = (bf16)xp_[3];                   \
                    g_[4] = (bf16)xp_[4];                                         \
                    g_[5] = (bf16)1.0f;   /* bias-1 slot (k=37) */                \
                }                                                                 \
            }                                                                     \
            A0[j_] = f_;                                                          \
            A1[j_] = g_;                                                          \
        }                                                                         \
    } while (0)

// Cross-lane flush of the open segment: reduce over the mr bits (4x shfl_xor),
// atomicAdd from the 4 mr==0 lanes (one per q = feature quad).
#define FLUSH()                                                            \
    do {                                                                   \
        _Pragma("unroll")                                                  \
        for (int m_ = 1; m_ <= 8; m_ <<= 1) {                              \
            _Pragma("unroll")                                              \
            for (int r_ = 0; r_ < 4; ++r_) {                               \
                accLo[r_] += __shfl_xor(accLo[r_], m_, 64);                \
                accHi[r_] += __shfl_xor(accHi[r_], m_, 64);                \
            }                                                              \
        }                                                                  \
        if (mr == 0) {                                                     \
            _Pragma("unroll")                                              \
            for (int r_ = 0; r_ < 4; ++r_) {                               \
                atomicAdd(&out[accSeg * NE + q * 4 + r_],      accLo[r_]); \
                atomicAdd(&out[accSeg * NE + 16 + q * 4 + r_], accHi[r_]); \
            }                                                              \
        }                                                                  \
    } while (0)

// Persistent-chunk kernel; per-wave-private LDS, no __syncthreads.
// This round: registers shaved to cross the 3-waves/SIMD residency threshold.
//  (a) epilogue fused per-j (one node per mr lane) -> dLo/dHi[4] arrays gone;
//  (b) b3 pre-folded into out[] by init_out (out = len(s)*b3) -> b3f regs gone,
//      phase-C accumulators init to 0;
//  (c) __launch_bounds__(256,3) to pin 3 waves/EU.
__global__ __launch_bounds__(256, 3)
void dag_mfma_kernel(const float* __restrict__ h_node,
                     const float* __restrict__ x,
                     const float* __restrict__ W1, const float* __restrict__ b1,
                     const float* __restrict__ W2, const float* __restrict__ b2,
                     const float* __restrict__ W3, const float* __restrict__ b3,
                     const int* __restrict__ ptr,
                     float* __restrict__ out) {
    __shared__ __align__(16) char sBuf[16 * TILE_BYTES];   // 36,864 B (4 waves)

    const int tid = threadIdx.x;
    const int w   = tid >> 6;
    const int l   = tid & 63;
    const int q   = l >> 4;
    const int mr  = l & 15;

    const int wStart = blockIdx.x * CHUNK + w * WCHUNK;
    if (wStart >= NUM_NODES) return;          // safe: no barriers in this kernel

    const int pstride = (ptr[NUM_DAGS] == NUM_NODES) ? 1 : 2;

    // ---- issue group-0 activation loads first (start HBM fetch early) ----
    bf16x8 a0c[4], a1c[4];
    bf16x8 a0n[4] = {}, a1n[4] = {};
    LOADG(wStart, a0c, a1c);

    // ---- weight A-fragments (once per block; L2-resident) ----
    bf16x8 w1f[2][4], w2f[2][4], w3f[2][2];
    #pragma unroll
    for (int s = 0; s < 2; ++s) {
        #pragma unroll
        for (int mt = 0; mt < 4; ++mt) {
            #pragma unroll
            for (int j = 0; j < 8; ++j) {
                const int kk  = s * 32 + q * 8 + j;
                const int col = mt * 16 + mr;
                float v1;
                if      (kk < 32)  v1 = W1[(kk + 5) * 64 + col];
                else if (kk < 37)  v1 = W1[(kk - 32) * 64 + col];
                else if (kk == 37) v1 = b1[col];
                else               v1 = 0.0f;
                w1f[s][mt][j] = (bf16)v1;
                w2f[s][mt][j] = (bf16)W2[kk * 64 + col];
                if (mt < 2) w3f[s][mt][j] = (bf16)W3[kk * 32 + mt * 16 + mr];
            }
        }
    }
    floatx4 b2f[4];
    #pragma unroll
    for (int mt = 0; mt < 4; ++mt)
        b2f[mt] = *(const floatx4*)(b2 + mt * 16 + q * 4);

    // one binary search per wave; tracked incrementally afterwards
    int seg = seg_of(ptr, wStart, pstride);

    // running per-lane partial sums for the currently-open segment
    int accSeg = seg;
    floatx4 accLo = {}, accHi = {};

    char* myBuf = sBuf + w * WAVE_LDS;

    for (int g = 0; g < NGROUPS; ++g) {
        const int gLo = wStart + g * 64;
        if (gLo >= NUM_NODES) break;

        // prefetch next group's activations (hidden under the MFMA phases)
        if (g + 1 < NGROUPS) LOADG(gLo + 64, a0n, a1n);

        // ---- phase A: layer 1 (reg frags -> relu -> LDS) ----
        #pragma unroll
        for (int j = 0; j < 4; ++j) {
            floatx4 c[4] = {};
            #pragma unroll
            for (int mt = 0; mt < 4; ++mt) {
                c[mt] = MFMA(w1f[0][mt], a0c[j], c[mt]);
                c[mt] = MFMA(w1f[1][mt], a1c[j], c[mt]);
            }
            char* tb = myBuf + j * TILE_BYTES + mr * ROW_BYTES;
            #pragma unroll
            for (int mt = 0; mt < 4; ++mt) {
                bf16x4 v;
                v[0] = (bf16)fmaxf(c[mt][0], 0.0f);
                v[1] = (bf16)fmaxf(c[mt][1], 0.0f);
                v[2] = (bf16)fmaxf(c[mt][2], 0.0f);
                v[3] = (bf16)fmaxf(c[mt][3], 0.0f);
                *(bf16x4*)(tb + mt * 32 + q * 8) = v;   // feats mt*16+q*4.. of node mr
            }
        }

        // ---- phase B: layer 2 (LDS -> relu -> LDS in place; DS in-order/wave) ----
        #pragma unroll
        for (int j = 0; j < 4; ++j) {
            char* tb = myBuf + j * TILE_BYTES + mr * ROW_BYTES;
            bf16x8 h0 = *(const bf16x8*)(tb + q * 16);        // feats q*8..+7
            bf16x8 h1 = *(const bf16x8*)(tb + 64 + q * 16);   // feats 32+q*8..+7
            floatx4 c[4];
            #pragma unroll
            for (int mt = 0; mt < 4; ++mt) {
                c[mt] = b2f[mt];
                c[mt] = MFMA(w2f[0][mt], h0, c[mt]);
                c[mt] = MFMA(w2f[1][mt], h1, c[mt]);
            }
            #pragma unroll
            for (int mt = 0; mt < 4; ++mt) {
                bf16x4 v;
                v[0] = (bf16)fmaxf(c[mt][0], 0.0f);
                v[1] = (bf16)fmaxf(c[mt][1], 0.0f);
                v[2] = (bf16)fmaxf(c[mt][2], 0.0f);
                v[3] = (bf16)fmaxf(c[mt][3], 0.0f);
                *(bf16x4*)(tb + mt * 32 + q * 8) = v;
            }
        }

        // ---- phase C + fused per-j epilogue ----
        // D layout: lane (q,mr) holds feats q*4+r (d0) and 16+q*4+r (d1) of
        // node jLo + mr -- exactly ONE node per lane per j-slice.
        #pragma unroll
        for (int j = 0; j < 4; ++j) {
            char* tb = myBuf + j * TILE_BYTES + mr * ROW_BYTES;
            bf16x8 p0 = *(const bf16x8*)(tb + q * 16);
            bf16x8 p1 = *(const bf16x8*)(tb + 64 + q * 16);
            floatx4 d0 = {}, d1 = {};            // b3 pre-folded into out[]
            d0 = MFMA(w3f[0][0], p0, d0);
            d0 = MFMA(w3f[1][0], p1, d0);
            d1 = MFMA(w3f[0][1], p0, d1);
            d1 = MFMA(w3f[1][1], p1, d1);

            const int jLo = gLo + j * 16;
            if (jLo >= NUM_NODES) break;         // tail: remaining slices empty
            const int jEnd = (jLo + 16 < NUM_NODES) ? jLo + 16 : NUM_NODES;

            while (ptr[(seg + 1) * pstride] <= jLo) ++seg;
            int segLast = seg;
            while (ptr[(segLast + 1) * pstride] <= jEnd - 1) ++segLast;

            if (seg == segLast && seg == accSeg) {
                // whole slice in the open segment (OOB-tail lanes have d==0)
                accLo += d0; accHi += d1;
            } else {
                const int node = jLo + mr;
                for (int s = seg; s <= segLast; ++s) {
                    int lo = ptr[s * pstride];
                    int hi = ptr[(s + 1) * pstride];
                    if (lo < jLo) lo = jLo;
                    if (hi > jEnd) hi = jEnd;
                    if (hi <= lo) continue;       // empty segment
                    floatx4 pLo = {}, pHi = {};
                    if (node >= lo && node < hi) { pLo = d0; pHi = d1; }
                    if (s == accSeg) {
                        accLo += pLo; accHi += pHi;
                    } else {
                        FLUSH();
                        accLo = pLo; accHi = pHi; accSeg = s;
                    }
                }
            }
            seg = segLast;
        }

        // rotate prefetch buffers (static indices; becomes register renames)
        #pragma unroll
        for (int j = 0; j < 4; ++j) { a0c[j] = a0n[j]; a1c[j] = a1n[j]; }
    }

    // ---- final flush of the open segment ----
    FLUSH();
}

// out[s][f] = len(s) * b3[f]  (replaces memset; folds the per-node +b3 term)
__global__ __launch_bounds__(256)
void init_out(const int* __restrict__ ptr, const float* __restrict__ b3,
              float* __restrict__ out) {
    const int i = blockIdx.x * 256 + threadIdx.x;
    if (i >= NUM_DAGS * NE) return;
    const int s = i >> 5, f = i & 31;
    const int pst = (ptr[NUM_DAGS] == NUM_NODES) ? 1 : 2;
    const int len = ptr[(s + 1) * pst] - ptr[s * pst];
    out[i] = (float)len * b3[f];
}

extern "C" void kernel_launch(void* const* d_in, const int* in_sizes, int n_in,
                              void* d_out, int out_size, void* d_ws, size_t ws_size,
                              hipStream_t stream) {
    const float* h_node = (const float*)d_in[0];
    const float* x      = (const float*)d_in[1];
    const float* W1     = (const float*)d_in[2];
    const float* b1     = (const float*)d_in[3];
    const float* W2     = (const float*)d_in[4];
    const float* b2     = (const float*)d_in[5];
    const float* W3     = (const float*)d_in[6];
    const float* b3     = (const float*)d_in[7];
    const int*   ptr    = (const int*)d_in[8];
    float* out          = (float*)d_out;

    const int initGrid = (NUM_DAGS * NE + 255) / 256;
    init_out<<<initGrid, 256, 0, stream>>>(ptr, b3, out);

    const int grid = (NUM_NODES + CHUNK - 1) / CHUNK;   // 977 blocks, 2048 nodes each
    dag_mfma_kernel<<<grid, 256, 0, stream>>>(h_node, x, W1, b1, W2, b2,
                                              W3, b3, ptr, out);
}

// Round 7
// 432.402 us; speedup vs baseline: 1.3644x; 1.3644x over previous
//
#include <hip/hip_runtime.h>
#include <hip/hip_bf16.h>

typedef __bf16 bf16;
typedef __bf16 bf16x4 __attribute__((ext_vector_type(4)));
typedef __bf16 bf16x8 __attribute__((ext_vector_type(8)));
typedef float  floatx4 __attribute__((ext_vector_type(4)));

#define NUM_NODES 2000000
#define NUM_DAGS  20000
#define NE 32

#define MFMA(a, b, c) __builtin_amdgcn_mfma_f32_16x16x32_bf16((a), (b), (c), 0, 0, 0)

#define ROW_BYTES  144                 // 16 nodes/tile, 144 B per node-row
#define TILE_BYTES (16 * ROW_BYTES)    // 2304 B
#define WAVE_LDS   (4 * TILE_BYTES)    // 9216 B: one 64-node group per wave
#define WCHUNK     512                 // nodes per wave (contiguous)
#define NGROUPS    (WCHUNK / 64)       // 8 groups of 64 nodes
#define CHUNK      (4 * WCHUNK)        // 2048 nodes per block
#define CAP_B      160                 // cached segment boundaries per wave

// NOTE: NUM_NODES % 64 == 0, so every active 16-node j-slice is fully in
// range (no partially-OOB lanes reach the epilogue fast path).

// Find largest s in [0, NUM_DAGS-1] with ptr[s*st] <= n.
// st = 1 for int32 ptr, 2 for int64 (little-endian low words).
__device__ __forceinline__ int seg_of(const int* __restrict__ ptr, int n, int st) {
    int lo = 0, hi = NUM_DAGS;
    while (hi - lo > 1) {
        int mid = (lo + hi) >> 1;
        if (ptr[mid * st] <= n) lo = mid; else hi = mid;
    }
    return lo;
}

// Load activation B-fragments for one 64-node group starting at gBase.
// A0: h_node k=0..31 frag; A1: x/bias k=32..63 frag (only q==0 lanes non-zero).
#define LOADG(gBase, A0, A1)                                                      \
    do {                                                                          \
        _Pragma("unroll")                                                         \
        for (int j_ = 0; j_ < 4; ++j_) {                                          \
            const int node_ = (gBase) + j_ * 16 + mr;                             \
            bf16x8 f_ = {};                                                       \
            bf16x8 g_ = {};                                                       \
            if (node_ < NUM_NODES) {                                              \
                const floatx4* hp_ =                                              \
                    (const floatx4*)(h_node + (size_t)node_ * 32 + q * 8);        \
                floatx4 v0_ = hp_[0], v1_ = hp_[1];                               \
                f_[0] = (bf16)v0_[0]; f_[1] = (bf16)v0_[1];                       \
                f_[2] = (bf16)v0_[2]; f_[3] = (bf16)v0_[3];                       \
                f_[4] = (bf16)v1_[0]; f_[5] = (bf16)v1_[1];                       \
                f_[6] = (bf16)v1_[2]; f_[7] = (bf16)v1_[3];                       \
                if (q == 0) {                                                     \
                    const float* xp_ = x + (size_t)node_ * 5;                     \
                    g_[0] = (bf16)xp_[0]; g_[1] = (bf16)xp_[1];                   \
                    g_[2] = (bf16)xp_[2]; g_[3] = (bf16)xp_[3];                   \
                    g_[4] = (bf16)xp_[4];                                         \
                    g_[5] = (bf16)1.0f;   /* bias-1 slot (k=37) */                \
                }                                                                 \
            }                                                                     \
            A0[j_] = f_;                                                          \
            A1[j_] = g_;                                                          \
        }                                                                         \
    } while (0)

// Cross-lane flush of the open segment: reduce over the mr bits (4x shfl_xor),
// atomicAdd from the 4 mr==0 lanes (one per q = feature quad).
#define FLUSH()                                                            \
    do {                                                                   \
        _Pragma("unroll")                                                  \
        for (int m_ = 1; m_ <= 8; m_ <<= 1) {                              \
            _Pragma("unroll")                                              \
            for (int r_ = 0; r_ < 4; ++r_) {                               \
                accLo[r_] += __shfl_xor(accLo[r_], m_, 64);                \
                accHi[r_] += __shfl_xor(accHi[r_], m_, 64);                \
            }                                                              \
        }                                                                  \
        if (mr == 0) {                                                     \
            _Pragma("unroll")                                              \
            for (int r_ = 0; r_ < 4; ++r_) {                               \
                atomicAdd(&out[accSeg * NE + q * 4 + r_],      accLo[r_]); \
                atomicAdd(&out[accSeg * NE + 16 + q * 4 + r_], accHi[r_]); \
            }                                                              \
        }                                                                  \
    } while (0)

// Boundary accessor: LDS cache for the common case, global fallback past CAP_B.
#define BND(i) (((i) < CAP_B) ? bc[(i)] : ptr[(segFirst + (i)) * pstride])

// Persistent-chunk kernel; per-wave-private LDS, no __syncthreads.
// vmcnt-hygiene round:
//  (a) segment boundaries cached in LDS per wave -> NO data-dependent global
//      loads in the main loop (LDS uses lgkmcnt; prefetch vmcnt undisturbed);
//  (b) body reordered compute -> epilogue(atomics) -> rotate(drain) -> LOADG,
//      so the conservative vmcnt(0) lands BEFORE new loads issue and the
//      prefetch stays in flight across the entire next body;
//  (c) launch_bounds (256,2) -- (256,3) caused scratch spills (+220 MB HBM
//      traffic, 2x regression in round 5).
__global__ __launch_bounds__(256, 2)
void dag_mfma_kernel(const float* __restrict__ h_node,
                     const float* __restrict__ x,
                     const float* __restrict__ W1, const float* __restrict__ b1,
                     const float* __restrict__ W2, const float* __restrict__ b2,
                     const float* __restrict__ W3, const float* __restrict__ b3,
                     const int* __restrict__ ptr,
                     float* __restrict__ out) {
    __shared__ __align__(16) char sBuf[16 * TILE_BYTES];   // 36,864 B (4 waves)
    __shared__ int sBnd[4][CAP_B];                         //  2,560 B

    const int tid = threadIdx.x;
    const int w   = tid >> 6;
    const int l   = tid & 63;
    const int q   = l >> 4;
    const int mr  = l & 15;

    const int wStart = blockIdx.x * CHUNK + w * WCHUNK;
    if (wStart >= NUM_NODES) return;          // safe: no barriers in this kernel

    const int pstride = (ptr[NUM_DAGS] == NUM_NODES) ? 1 : 2;

    // ---- issue group-0 activation loads first (start HBM fetch early) ----
    bf16x8 a0c[4], a1c[4];
    bf16x8 a0n[4] = {}, a1n[4] = {};
    LOADG(wStart, a0n, a1n);

    // ---- weight A-fragments (once per block; L2-resident) ----
    bf16x8 w1f[2][4], w2f[2][4], w3f[2][2];
    #pragma unroll
    for (int s = 0; s < 2; ++s) {
        #pragma unroll
        for (int mt = 0; mt < 4; ++mt) {
            #pragma unroll
            for (int j = 0; j < 8; ++j) {
                const int kk  = s * 32 + q * 8 + j;
                const int col = mt * 16 + mr;
                float v1;
                if      (kk < 32)  v1 = W1[(kk + 5) * 64 + col];
                else if (kk < 37)  v1 = W1[(kk - 32) * 64 + col];
                else if (kk == 37) v1 = b1[col];
                else               v1 = 0.0f;
                w1f[s][mt][j] = (bf16)v1;
                w2f[s][mt][j] = (bf16)W2[kk * 64 + col];
                if (mt < 2) w3f[s][mt][j] = (bf16)W3[kk * 32 + mt * 16 + mr];
            }
        }
    }
    floatx4 b2f[4];
    #pragma unroll
    for (int mt = 0; mt < 4; ++mt)
        b2f[mt] = *(const floatx4*)(b2 + mt * 16 + q * 4);

    // ---- per-wave segment span + LDS boundary cache (one-time) ----
    const int wEndN    = (wStart + WCHUNK < NUM_NODES) ? wStart + WCHUNK : NUM_NODES;
    const int segFirst = seg_of(ptr, wStart, pstride);
    const int segLastW = seg_of(ptr, wEndN - 1, pstride);
    const int nB       = segLastW - segFirst + 2;   // boundaries ptr[segFirst..segLastW+1]
    int* bc = sBnd[w];
    for (int i = l; i < nB && i < CAP_B; i += 64)
        bc[i] = ptr[(segFirst + i) * pstride];
    // wave-private LDS, DS in-order per wave: no barrier needed.

    int si    = 0;                 // open segment = segFirst + si
    int nextB = BND(1);            // upper boundary of the open segment
    int accSeg = segFirst;
    floatx4 accLo = {}, accHi = {};

    char* myBuf = sBuf + w * WAVE_LDS;

    // finish prologue pipeline: a0c <- group 0, issue group 1
    #pragma unroll
    for (int j = 0; j < 4; ++j) { a0c[j] = a0n[j]; a1c[j] = a1n[j]; }
    LOADG(wStart + 64, a0n, a1n);

    #pragma unroll 1
    for (int g = 0; g < NGROUPS; ++g) {
        const int gLo = wStart + g * 64;
        if (gLo >= NUM_NODES) break;

        // ---- phase A: layer 1 (reg frags -> relu -> LDS) ----
        #pragma unroll
        for (int j = 0; j < 4; ++j) {
            floatx4 c[4] = {};
            #pragma unroll
            for (int mt = 0; mt < 4; ++mt) {
                c[mt] = MFMA(w1f[0][mt], a0c[j], c[mt]);
                c[mt] = MFMA(w1f[1][mt], a1c[j], c[mt]);
            }
            char* tb = myBuf + j * TILE_BYTES + mr * ROW_BYTES;
            #pragma unroll
            for (int mt = 0; mt < 4; ++mt) {
                bf16x4 v;
                v[0] = (bf16)fmaxf(c[mt][0], 0.0f);
                v[1] = (bf16)fmaxf(c[mt][1], 0.0f);
                v[2] = (bf16)fmaxf(c[mt][2], 0.0f);
                v[3] = (bf16)fmaxf(c[mt][3], 0.0f);
                *(bf16x4*)(tb + mt * 32 + q * 8) = v;   // feats mt*16+q*4.. of node mr
            }
        }

        // ---- phase B: layer 2 (LDS -> relu -> LDS in place; DS in-order/wave) ----
        #pragma unroll
        for (int j = 0; j < 4; ++j) {
            char* tb = myBuf + j * TILE_BYTES + mr * ROW_BYTES;
            bf16x8 h0 = *(const bf16x8*)(tb + q * 16);        // feats q*8..+7
            bf16x8 h1 = *(const bf16x8*)(tb + 64 + q * 16);   // feats 32+q*8..+7
            floatx4 c[4];
            #pragma unroll
            for (int mt = 0; mt < 4; ++mt) {
                c[mt] = b2f[mt];
                c[mt] = MFMA(w2f[0][mt], h0, c[mt]);
                c[mt] = MFMA(w2f[1][mt], h1, c[mt]);
            }
            #pragma unroll
            for (int mt = 0; mt < 4; ++mt) {
                bf16x4 v;
                v[0] = (bf16)fmaxf(c[mt][0], 0.0f);
                v[1] = (bf16)fmaxf(c[mt][1], 0.0f);
                v[2] = (bf16)fmaxf(c[mt][2], 0.0f);
                v[3] = (bf16)fmaxf(c[mt][3], 0.0f);
                *(bf16x4*)(tb + mt * 32 + q * 8) = v;
            }
        }

        // ---- phase C + fused per-j epilogue (boundaries from LDS cache) ----
        // D layout: lane (q,mr) holds feats q*4+r (d0) and 16+q*4+r (d1) of
        // node jLo + mr -- exactly ONE node per lane per j-slice.
        #pragma unroll
        for (int j = 0; j < 4; ++j) {
            char* tb = myBuf + j * TILE_BYTES + mr * ROW_BYTES;
            bf16x8 p0 = *(const bf16x8*)(tb + q * 16);
            bf16x8 p1 = *(const bf16x8*)(tb + 64 + q * 16);
            floatx4 d0 = {}, d1 = {};            // b3 pre-folded into out[]
            d0 = MFMA(w3f[0][0], p0, d0);
            d0 = MFMA(w3f[1][0], p1, d0);
            d1 = MFMA(w3f[0][1], p0, d1);
            d1 = MFMA(w3f[1][1], p1, d1);

            const int jLo = gLo + j * 16;
            if (jLo >= NUM_NODES) break;         // tail: remaining slices empty
            const int jEnd = jLo + 16;           // NUM_NODES % 16 == 0
            const int node = jLo + mr;

            // advance open segment: BND(si) <= jLo < nextB (register-only when
            // no advance; LDS read only on the ~15% of slices with a boundary)
            while (nextB <= jLo) { ++si; nextB = BND(si + 1); }
            const int segA = segFirst + si;

            if (nextB >= jEnd) {
                // whole slice inside the open segment (85% path)
                if (segA == accSeg) { accLo += d0; accHi += d1; }
                else { FLUSH(); accSeg = segA; accLo = d0; accHi = d1; }
            } else {
                // walk boundaries inside this slice
                int lob = jLo, s = segA, nb = nextB;
                while (true) {
                    const int hib = (nb < jEnd) ? nb : jEnd;
                    if (hib > lob) {             // skip empty segments
                        floatx4 pLo = {}, pHi = {};
                        if (node >= lob && node < hib) { pLo = d0; pHi = d1; }
                        if (s == accSeg) { accLo += pLo; accHi += pHi; }
                        else { FLUSH(); accSeg = s; accLo = pLo; accHi = pHi; }
                    }
                    if (nb >= jEnd) break;
                    lob = nb; ++si; s = segFirst + si; nextB = BND(si + 1); nb = nextB;
                }
            }
        }

        // ---- rotate (conservative vmcnt drain lands HERE, before new loads;
        //      anti-dependence a0n -> a0c pins this before the LOADG below) ----
        if (g + 1 < NGROUPS) {
            #pragma unroll
            for (int j = 0; j < 4; ++j) { a0c[j] = a0n[j]; a1c[j] = a1n[j]; }
            // ---- issue next-next group's loads; in flight across body g+1 ----
            if (g + 2 < NGROUPS) LOADG(gLo + 128, a0n, a1n);
        }
    }

    // ---- final flush of the open segment ----
    FLUSH();
}

// out[s][f] = len(s) * b3[f]  (replaces memset; folds the per-node +b3 term)
__global__ __launch_bounds__(256)
void init_out(const int* __restrict__ ptr, const float* __restrict__ b3,
              float* __restrict__ out) {
    const int i = blockIdx.x * 256 + threadIdx.x;
    if (i >= NUM_DAGS * NE) return;
    const int s = i >> 5, f = i & 31;
    const int pst = (ptr[NUM_DAGS] == NUM_NODES) ? 1 : 2;
    const int len = ptr[(s + 1) * pst] - ptr[s * pst];
    out[i] = (float)len * b3[f];
}

extern "C" void kernel_launch(void* const* d_in, const int* in_sizes, int n_in,
                              void* d_out, int out_size, void* d_ws, size_t ws_size,
                              hipStream_t stream) {
    const float* h_node = (const float*)d_in[0];
    const float* x      = (const float*)d_in[1];
    const float* W1     = (const float*)d_in[2];
    const float* b1     = (const float*)d_in[3];
    const float* W2     = (const float*)d_in[4];
    const float* b2     = (const float*)d_in[5];
    const float* W3     = (const float*)d_in[6];
    const float* b3     = (const float*)d_in[7];
    const int*   ptr    = (const int*)d_in[8];
    float* out          = (float*)d_out;

    const int initGrid = (NUM_DAGS * NE + 255) / 256;
    init_out<<<initGrid, 256, 0, stream>>>(ptr, b3, out);

    const int grid = (NUM_NODES + CHUNK - 1) / CHUNK;   // 977 blocks, 2048 nodes each
    dag_mfma_kernel<<<grid, 256, 0, stream>>>(h_node, x, W1, b1, W2, b2,
                                              W3, b3, ptr, out);
}